// Round 12
// baseline (64.749 us; speedup 1.0000x reference)
//
#include <hip/hip_runtime.h>
#include <hip/hip_bf16.h>
#include <stdint.h>

#define LEAKY_ALPHA 0.2f

using f32x4 = __attribute__((ext_vector_type(4))) float;
using u32x2 = __attribute__((ext_vector_type(2))) unsigned int;
using u32x4 = __attribute__((ext_vector_type(4))) unsigned int;
using i32x4 = __attribute__((ext_vector_type(4))) int;
using s16x8 = __attribute__((ext_vector_type(8))) short;

static __device__ __forceinline__ unsigned short f2bf(float x) {
  __hip_bfloat16 b = __float2bfloat16(x);
  return __builtin_bit_cast(unsigned short, b);
}

// ---------------------------------------------------------------------------
// Prep: WT[o][f] = bf16(W[f][o]);  wsum[f] = sum_o W[f][o]  (for exact fp32 s)
// ---------------------------------------------------------------------------
__global__ __launch_bounds__(256) void gat_prep(
    const float* __restrict__ W, __hip_bfloat16* __restrict__ WT,
    float* __restrict__ wsum)
{
  const int o = blockIdx.x;   // doubles as f-row index for wsum
  const int t = threadIdx.x;  // 256
  WT[o * 256 + t] = __float2bfloat16(W[t * 256 + o]);
  float u = W[o * 256 + t];
#pragma unroll
  for (int off = 1; off < 64; off <<= 1) u += __shfl_xor(u, off, 64);
  __shared__ float red[4];
  if ((t & 63) == 0) red[t >> 6] = u;
  __syncthreads();
  if (t == 0) wsum[o] = red[0] + red[1] + red[2] + red[3];
}

// ---------------------------------------------------------------------------
// Kernel A: WhT[b][o][q] = bf16( (h @ W)^T ) via MFMA; s[b][q] = h[q,:]·wsum
// (fp32 exact). q-tile 32: grid 512 for TLP. Block = 32 q x 256 o.
// ---------------------------------------------------------------------------
__global__ __launch_bounds__(256, 3) void gat_wh2(
    const float* __restrict__ h, const __hip_bfloat16* __restrict__ WT,
    const float* __restrict__ wsum, __hip_bfloat16* __restrict__ WhT,
    float* __restrict__ s)
{
  const int b = blockIdx.x >> 6;
  const int q0 = (blockIdx.x & 63) * 32;
  const int t = threadIdx.x;
  const int wid = t >> 6, lane = t & 63;

  __shared__ __align__(16) unsigned char Bh[32 * 512];   // h bf16 [32q][256f] swz
  __shared__ __align__(16) unsigned char Aw[256 * 128];  // WT bf16 [256o][64f] swz
  __shared__ __align__(16) float wsl[256];

  wsl[t] = wsum[t];
  __syncthreads();

  // stage h -> Bh (bf16, swizzled) with fused fp32 s computation
  {
    const int q = t >> 3;                 // 32 rows, 8 thr/row
    const int fs = (t & 7) * 32;          // 32 f per thread
    const float* hrow = h + ((size_t)(b * 2048 + q0 + q)) * 256 + fs;
    float sp = 0.f;
#pragma unroll
    for (int c = 0; c < 4; ++c) {
      const f32x4 a  = *(const f32x4*)&hrow[c * 8];
      const f32x4 bq = *(const f32x4*)&hrow[c * 8 + 4];
      const f32x4 wa = *(const f32x4*)&wsl[fs + c * 8];
      const f32x4 wb = *(const f32x4*)&wsl[fs + c * 8 + 4];
      sp += a[0]*wa[0] + a[1]*wa[1] + a[2]*wa[2] + a[3]*wa[3]
          + bq[0]*wb[0] + bq[1]*wb[1] + bq[2]*wb[2] + bq[3]*wb[3];
      u32x4 pk;
      pk[0] = (unsigned)f2bf(a[0])  | ((unsigned)f2bf(a[1])  << 16);
      pk[1] = (unsigned)f2bf(a[2])  | ((unsigned)f2bf(a[3])  << 16);
      pk[2] = (unsigned)f2bf(bq[0]) | ((unsigned)f2bf(bq[1]) << 16);
      pk[3] = (unsigned)f2bf(bq[2]) | ((unsigned)f2bf(bq[3]) << 16);
      const int boff = q * 512 + ((fs * 2 + c * 16) ^ ((q & 7) << 4));
      *(u32x4*)&Bh[boff] = pk;
    }
    sp += __shfl_xor(sp, 1, 64);
    sp += __shfl_xor(sp, 2, 64);
    sp += __shfl_xor(sp, 4, 64);
    if ((t & 7) == 0) s[b * 2048 + q0 + q] = sp;
  }

  f32x4 acc[2][4];
#pragma unroll
  for (int i = 0; i < 2; ++i)
#pragma unroll
    for (int j = 0; j < 4; ++j) acc[i][j] = (f32x4)(0.f);

  for (int it = 0; it < 4; ++it) {
    const int f0 = it * 64;
    __syncthreads();   // it=0: Bh visible; it>0: protect Aw from prev reads
#pragma unroll
    for (int j = 0; j < 8; ++j) {
      const int o = (t >> 3) + 32 * j;
      const int c = t & 7;
      const u32x4 v = *(const u32x4*)&WT[o * 256 + f0 + c * 8];
      *(u32x4*)&Aw[o * 128 + ((c * 16) ^ ((o & 7) << 4))] = v;
    }
    __syncthreads();
#pragma unroll
    for (int kt = 0; kt < 2; ++kt) {
      const int kb = kt * 64 + ((lane >> 4) << 4);   // byte off within 64-f span
      s16x8 af[2], bf[4];
#pragma unroll
      for (int qt = 0; qt < 2; ++qt) {
        const int qr = qt * 16 + (lane & 15);
        af[qt] = *(const s16x8*)&Bh[qr * 512 + ((f0 * 2 + kb) ^ ((qr & 7) << 4))];
      }
#pragma unroll
      for (int ot = 0; ot < 4; ++ot) {
        const int orow = wid * 64 + ot * 16 + (lane & 15);
        bf[ot] = *(const s16x8*)&Aw[orow * 128 + (kb ^ ((orow & 7) << 4))];
      }
#pragma unroll
      for (int qt = 0; qt < 2; ++qt)
#pragma unroll
        for (int ot = 0; ot < 4; ++ot)
          acc[qt][ot] = __builtin_amdgcn_mfma_f32_16x16x32_bf16(
              af[qt], bf[ot], acc[qt][ot], 0, 0, 0);
    }
  }

  // epilogue: WhT[b][o][q0+q]; C-row = q (r contiguous) -> 8B vector stores
  __hip_bfloat16* __restrict__ WhTb = WhT + (size_t)b * 256 * 2048;
#pragma unroll
  for (int qt = 0; qt < 2; ++qt)
#pragma unroll
    for (int ot = 0; ot < 4; ++ot) {
      const int o = wid * 64 + ot * 16 + (lane & 15);
      const int ql = q0 + qt * 16 + ((lane >> 4) << 2);
      u32x2 pk;
      pk[0] = (unsigned)f2bf(acc[qt][ot][0]) | ((unsigned)f2bf(acc[qt][ot][1]) << 16);
      pk[1] = (unsigned)f2bf(acc[qt][ot][2]) | ((unsigned)f2bf(acc[qt][ot][3]) << 16);
      *(u32x2*)&WhTb[(size_t)o * 2048 + ql] = pk;
    }
}

// ---------------------------------------------------------------------------
// Kernel B: fused masked-softmax + PV, r3 schedule at 4-blocks/CU geometry.
// Block = 32p x 128o (o-split), 256 thr, 4 waves of 32p x 32o. Grid 1024 ->
// 4 independent blocks/CU (LDS exactly 40KB: red_sh/l_sh ALIASED into Wt[0];
// safe: red_sh consumed before first Wt[0] write (extra prologue barrier),
// l_sh written only after last Wt[0] read). Fixed bound m_p, dbuf LDS, one
// lgkm-drain barrier per 64-q tile, reg-prefetch across the barrier.
// ---------------------------------------------------------------------------
__global__ __launch_bounds__(256, 4) void gat_attn(
    const int* __restrict__ adj, const float* __restrict__ s,
    const __hip_bfloat16* __restrict__ WhT, float* __restrict__ out)
{
  const int N = 2048;
  const int bid = blockIdx.x;
  const int swz = (bid & 7) * 128 + (bid >> 3);  // XCD-major: batch == XCD
  const int b = swz >> 7;
  const int inner = swz & 127;
  const int p0 = (inner >> 1) * 32;              // o-halves of a ptile adjacent
  const int o0 = (inner & 1) * 128;
  const int t = threadIdx.x;
  const int wid = t >> 6, lane = t & 63;

  __shared__ __align__(16) unsigned char Bs[2][128 * 128]; // Wh tile dbuf 32KB
  __shared__ __align__(16) unsigned char Wt[2][32 * 128];  // P tile dbuf 8KB
  float* red_sh = (float*)&Wt[0][0];   // 4 floats, prologue-only
  float* l_sh   = (float*)&Wt[0][32];  // 32 floats, epilogue-only

  const int ep = t >> 3;              // p-row 0..31 (8 thr/row)
  const int eq8 = (t & 7) * 8;        // 8 q per thread
  const int* __restrict__ adjrow = adj + ((size_t)(b * N + p0 + ep)) * N;
  const float* __restrict__ sB = s + b * N;
  const __hip_bfloat16* __restrict__ WhTb =
      WhT + (size_t)b * 256 * 2048 + (size_t)o0 * 2048;

  const int so = t >> 3;              // Bs staging o-base 0..31 (+32j)
  const int q16 = t & 7;              // 16B chunk in 128B row

  // ---- prologue: prefetch tile 0 into regs ----
  i32x4 av0 = *(const i32x4*)&adjrow[eq8];
  i32x4 av1 = *(const i32x4*)&adjrow[eq8 + 4];
  f32x4 sv0 = *(const f32x4*)&sB[eq8];
  f32x4 sv1 = *(const f32x4*)&sB[eq8 + 4];
  u32x4 breg[4];
#pragma unroll
  for (int j = 0; j < 4; ++j)
    breg[j] = *(const u32x4*)&WhTb[(size_t)(so + 32 * j) * 2048 + q16 * 8];

  // ---- block-wide smax over s[b,:] (fixed softmax bound) ----
  const f32x4 sa = *(const f32x4*)&sB[t * 8];
  const f32x4 sc = *(const f32x4*)&sB[t * 8 + 4];
  float bm = fmaxf(fmaxf(fmaxf(sa[0], sa[1]), fmaxf(sa[2], sa[3])),
                   fmaxf(fmaxf(sc[0], sc[1]), fmaxf(sc[2], sc[3])));
#pragma unroll
  for (int off = 1; off < 64; off <<= 1) bm = fmaxf(bm, __shfl_xor(bm, off, 64));
  if (lane == 0) red_sh[wid] = bm;
  const float s_p = sB[p0 + ep];
  __syncthreads();
  const float smax = fmaxf(fmaxf(red_sh[0], red_sh[1]),
                           fmaxf(red_sh[2], red_sh[3]));
  __syncthreads();   // red_sh fully consumed before any Wt[0] write
  const float xm = s_p + smax;
  const float m_p = (xm > 0.f) ? xm : (LEAKY_ALPHA * xm);

  f32x4 acc[2][2];
#pragma unroll
  for (int pt = 0; pt < 2; ++pt)
#pragma unroll
    for (int ot = 0; ot < 2; ++ot) acc[pt][ot] = (f32x4)(0.f);
  float lacc = 0.f;

#define GAT_TILE(BI, QQ)                                                      \
  do {                                                                        \
    float wv[8];                                                              \
    _Pragma("unroll")                                                         \
    for (int i = 0; i < 4; ++i) {                                             \
      const float x = s_p + sv0[i];                                           \
      const float le = (x > 0.f) ? x : (LEAKY_ALPHA * x);                     \
      const float w = __expf(le - m_p);                                       \
      wv[i] = (av0[i] != 0) ? w : 0.f;                                        \
      lacc += wv[i];                                                          \
    }                                                                         \
    _Pragma("unroll")                                                         \
    for (int i = 0; i < 4; ++i) {                                             \
      const float x = s_p + sv1[i];                                           \
      const float le = (x > 0.f) ? x : (LEAKY_ALPHA * x);                     \
      const float w = __expf(le - m_p);                                       \
      wv[4 + i] = (av1[i] != 0) ? w : 0.f;                                    \
      lacc += wv[4 + i];                                                      \
    }                                                                         \
    {                                                                         \
      u32x4 pw;                                                               \
      _Pragma("unroll")                                                       \
      for (int k2 = 0; k2 < 4; ++k2)                                          \
        pw[k2] = (unsigned)f2bf(wv[2 * k2]) |                                 \
                 ((unsigned)f2bf(wv[2 * k2 + 1]) << 16);                      \
      *(u32x4*)&Wt[BI][ep * 128 + ((eq8 * 2) ^ ((ep & 7) << 4))] = pw;        \
    }                                                                         \
    _Pragma("unroll")                                                         \
    for (int j = 0; j < 4; ++j) {                                             \
      const int o = so + 32 * j;                                              \
      *(u32x4*)&Bs[BI][o * 128 + ((q16 * 16) ^ ((o & 7) << 4))] = breg[j];    \
    }                                                                         \
    if ((QQ) + 64 < N) {                                                      \
      av0 = *(const i32x4*)&adjrow[(QQ) + 64 + eq8];                          \
      av1 = *(const i32x4*)&adjrow[(QQ) + 64 + eq8 + 4];                      \
      sv0 = *(const f32x4*)&sB[(QQ) + 64 + eq8];                              \
      sv1 = *(const f32x4*)&sB[(QQ) + 64 + eq8 + 4];                          \
      _Pragma("unroll")                                                       \
      for (int j = 0; j < 4; ++j)                                             \
        breg[j] = *(const u32x4*)&WhTb[(size_t)(so + 32 * j) * 2048 +         \
                                       (QQ) + 64 + q16 * 8];                  \
    }                                                                         \
    asm volatile("s_waitcnt lgkmcnt(0)" ::: "memory");                        \
    __builtin_amdgcn_s_barrier();                                             \
    asm volatile("" ::: "memory");                                            \
    {                                                                         \
      s16x8 afr[2][2], bfr[2][2];                                             \
      _Pragma("unroll")                                                       \
      for (int pt = 0; pt < 2; ++pt)                                          \
        _Pragma("unroll")                                                     \
        for (int kt = 0; kt < 2; ++kt) {                                      \
          const int pa = pt * 16 + (lane & 15);                               \
          const int kb = kt * 64 + ((lane >> 4) << 4);                        \
          afr[pt][kt] =                                                       \
              *(const s16x8*)&Wt[BI][pa * 128 + (kb ^ ((pa & 7) << 4))];      \
        }                                                                     \
      _Pragma("unroll")                                                       \
      for (int ot = 0; ot < 2; ++ot)                                          \
        _Pragma("unroll")                                                     \
        for (int kt = 0; kt < 2; ++kt) {                                      \
          const int ob = wid * 32 + ot * 16 + (lane & 15);                    \
          const int kb = kt * 64 + ((lane >> 4) << 4);                        \
          bfr[ot][kt] =                                                       \
              *(const s16x8*)&Bs[BI][ob * 128 + (kb ^ ((ob & 7) << 4))];      \
        }                                                                     \
      _Pragma("unroll")                                                       \
      for (int pt = 0; pt < 2; ++pt)                                          \
        _Pragma("unroll")                                                     \
        for (int ot = 0; ot < 2; ++ot)                                        \
          _Pragma("unroll")                                                   \
          for (int kt = 0; kt < 2; ++kt)                                      \
            acc[pt][ot] = __builtin_amdgcn_mfma_f32_16x16x32_bf16(            \
                afr[pt][kt], bfr[ot][kt], acc[pt][ot], 0, 0, 0);              \
    }                                                                         \
  } while (0)

  for (int q0 = 0; q0 < N; q0 += 128) {
    GAT_TILE(0, q0);
    GAT_TILE(1, q0 + 64);
  }
#undef GAT_TILE

  // ---- l reduction: 8 threads per row -> l_sh (aliases Wt[0]; all Wt[0]
  // reads completed at barrier of the final tile) ----
  lacc += __shfl_xor(lacc, 1, 64);
  lacc += __shfl_xor(lacc, 2, 64);
  lacc += __shfl_xor(lacc, 4, 64);
  if ((t & 7) == 0) l_sh[ep] = lacc;
  __syncthreads();

  // ---- epilogue: divide by l, store fp32 ----
#pragma unroll
  for (int pt = 0; pt < 2; ++pt) {
    const f32x4 lv = *(const f32x4*)&l_sh[pt * 16 + ((lane >> 4) << 2)];
    f32x4 inv;
#pragma unroll
    for (int r = 0; r < 4; ++r) inv[r] = 1.f / lv[r];
#pragma unroll
    for (int ot = 0; ot < 2; ++ot) {
      const int o = o0 + wid * 32 + ot * 16 + (lane & 15);
#pragma unroll
      for (int r = 0; r < 4; ++r) {
        const int row = p0 + pt * 16 + ((lane >> 4) << 2) + r;
        out[((size_t)(b * N + row)) * 256 + o] = acc[pt][ot][r] * inv[r];
      }
    }
  }
}

extern "C" void kernel_launch(void* const* d_in, const int* in_sizes, int n_in,
                              void* d_out, int out_size, void* d_ws, size_t ws_size,
                              hipStream_t stream) {
  const float* h = (const float*)d_in[0];
  const int* adj = (const int*)d_in[1];
  const float* W = (const float*)d_in[2];
  float* out = (float*)d_out;

  char* ws = (char*)d_ws;
  __hip_bfloat16* WhT = (__hip_bfloat16*)ws;                              // 8 MiB
  float* s = (float*)(ws + (size_t)8 * 1024 * 1024);                      // 64 KiB
  __hip_bfloat16* WT = (__hip_bfloat16*)(ws + (size_t)8 * 1024 * 1024 + 65536);   // 128 KiB
  float* wsum = (float*)(ws + (size_t)8 * 1024 * 1024 + 65536 + 131072);  // 1 KiB

  gat_prep<<<256, 256, 0, stream>>>(W, WT, wsum);
  gat_wh2<<<512, 256, 0, stream>>>(h, WT, wsum, WhT, s);
  gat_attn<<<1024, 256, 0, stream>>>(adj, s, WhT, out);
}

// Round 13
// 56.680 us; speedup vs baseline: 1.1424x; 1.1424x over previous
//
#include <hip/hip_runtime.h>
#include <hip/hip_bf16.h>
#include <stdint.h>

#define LEAKY_ALPHA 0.2f

using f32x4 = __attribute__((ext_vector_type(4))) float;
using u32x2 = __attribute__((ext_vector_type(2))) unsigned int;
using u32x4 = __attribute__((ext_vector_type(4))) unsigned int;
using i32x4 = __attribute__((ext_vector_type(4))) int;
using s16x8 = __attribute__((ext_vector_type(8))) short;

static __device__ __forceinline__ unsigned short f2bf(float x) {
  __hip_bfloat16 b = __float2bfloat16(x);
  return __builtin_bit_cast(unsigned short, b);
}

// ---------------------------------------------------------------------------
// Prep: WT[o][f] = bf16(W[f][o]);  wsum[f] = sum_o W[f][o]  (for exact fp32 s)
// ---------------------------------------------------------------------------
__global__ __launch_bounds__(256) void gat_prep(
    const float* __restrict__ W, __hip_bfloat16* __restrict__ WT,
    float* __restrict__ wsum)
{
  const int o = blockIdx.x;   // doubles as f-row index for wsum
  const int t = threadIdx.x;  // 256
  WT[o * 256 + t] = __float2bfloat16(W[t * 256 + o]);
  float u = W[o * 256 + t];
#pragma unroll
  for (int off = 1; off < 64; off <<= 1) u += __shfl_xor(u, off, 64);
  __shared__ float red[4];
  if ((t & 63) == 0) red[t >> 6] = u;
  __syncthreads();
  if (t == 0) wsum[o] = red[0] + red[1] + red[2] + red[3];
}

// ---------------------------------------------------------------------------
// Kernel A: WhT[b][o][q] = bf16( (h @ W)^T ) via MFMA; s[b][q] = h[q,:]·wsum
// (fp32 exact). q-tile 32: grid 512 -> 2-3 blocks/CU for TLP.
// Block = 32 q x 256 o, K=256 in 4 f-tiles. 512 blocks x 256 thr.
// ---------------------------------------------------------------------------
__global__ __launch_bounds__(256, 3) void gat_wh2(
    const float* __restrict__ h, const __hip_bfloat16* __restrict__ WT,
    const float* __restrict__ wsum, __hip_bfloat16* __restrict__ WhT,
    float* __restrict__ s)
{
  const int b = blockIdx.x >> 6;
  const int q0 = (blockIdx.x & 63) * 32;
  const int t = threadIdx.x;
  const int wid = t >> 6, lane = t & 63;

  __shared__ __align__(16) unsigned char Bh[32 * 512];   // h bf16 [32q][256f] swz
  __shared__ __align__(16) unsigned char Aw[256 * 128];  // WT bf16 [256o][64f] swz
  __shared__ __align__(16) float wsl[256];

  wsl[t] = wsum[t];
  __syncthreads();

  // stage h -> Bh (bf16, swizzled) with fused fp32 s computation
  {
    const int q = t >> 3;                 // 32 rows, 8 thr/row
    const int fs = (t & 7) * 32;          // 32 f per thread
    const float* hrow = h + ((size_t)(b * 2048 + q0 + q)) * 256 + fs;
    float sp = 0.f;
#pragma unroll
    for (int c = 0; c < 4; ++c) {
      const f32x4 a  = *(const f32x4*)&hrow[c * 8];
      const f32x4 bq = *(const f32x4*)&hrow[c * 8 + 4];
      const f32x4 wa = *(const f32x4*)&wsl[fs + c * 8];
      const f32x4 wb = *(const f32x4*)&wsl[fs + c * 8 + 4];
      sp += a[0]*wa[0] + a[1]*wa[1] + a[2]*wa[2] + a[3]*wa[3]
          + bq[0]*wb[0] + bq[1]*wb[1] + bq[2]*wb[2] + bq[3]*wb[3];
      u32x4 pk;
      pk[0] = (unsigned)f2bf(a[0])  | ((unsigned)f2bf(a[1])  << 16);
      pk[1] = (unsigned)f2bf(a[2])  | ((unsigned)f2bf(a[3])  << 16);
      pk[2] = (unsigned)f2bf(bq[0]) | ((unsigned)f2bf(bq[1]) << 16);
      pk[3] = (unsigned)f2bf(bq[2]) | ((unsigned)f2bf(bq[3]) << 16);
      const int boff = q * 512 + ((fs * 2 + c * 16) ^ ((q & 7) << 4));
      *(u32x4*)&Bh[boff] = pk;
    }
    sp += __shfl_xor(sp, 1, 64);
    sp += __shfl_xor(sp, 2, 64);
    sp += __shfl_xor(sp, 4, 64);
    if ((t & 7) == 0) s[b * 2048 + q0 + q] = sp;
  }

  f32x4 acc[2][4];
#pragma unroll
  for (int i = 0; i < 2; ++i)
#pragma unroll
    for (int j = 0; j < 4; ++j) acc[i][j] = (f32x4)(0.f);

  for (int it = 0; it < 4; ++it) {
    const int f0 = it * 64;
    __syncthreads();   // it=0: Bh visible; it>0: protect Aw from prev reads
#pragma unroll
    for (int j = 0; j < 8; ++j) {
      const int o = (t >> 3) + 32 * j;
      const int c = t & 7;
      const u32x4 v = *(const u32x4*)&WT[o * 256 + f0 + c * 8];
      *(u32x4*)&Aw[o * 128 + ((c * 16) ^ ((o & 7) << 4))] = v;
    }
    __syncthreads();
#pragma unroll
    for (int kt = 0; kt < 2; ++kt) {
      const int kb = kt * 64 + ((lane >> 4) << 4);   // byte off within 64-f span
      s16x8 af[2], bf[4];
#pragma unroll
      for (int qt = 0; qt < 2; ++qt) {
        const int qr = qt * 16 + (lane & 15);
        af[qt] = *(const s16x8*)&Bh[qr * 512 + ((f0 * 2 + kb) ^ ((qr & 7) << 4))];
      }
#pragma unroll
      for (int ot = 0; ot < 4; ++ot) {
        const int orow = wid * 64 + ot * 16 + (lane & 15);
        bf[ot] = *(const s16x8*)&Aw[orow * 128 + (kb ^ ((orow & 7) << 4))];
      }
#pragma unroll
      for (int qt = 0; qt < 2; ++qt)
#pragma unroll
        for (int ot = 0; ot < 4; ++ot)
          acc[qt][ot] = __builtin_amdgcn_mfma_f32_16x16x32_bf16(
              af[qt], bf[ot], acc[qt][ot], 0, 0, 0);
    }
  }

  // epilogue: WhT[b][o][q0+q]; C-row = q (r contiguous) -> 8B vector stores
  __hip_bfloat16* __restrict__ WhTb = WhT + (size_t)b * 256 * 2048;
#pragma unroll
  for (int qt = 0; qt < 2; ++qt)
#pragma unroll
    for (int ot = 0; ot < 4; ++ot) {
      const int o = wid * 64 + ot * 16 + (lane & 15);
      const int ql = q0 + qt * 16 + ((lane >> 4) << 2);
      u32x2 pk;
      pk[0] = (unsigned)f2bf(acc[qt][ot][0]) | ((unsigned)f2bf(acc[qt][ot][1]) << 16);
      pk[1] = (unsigned)f2bf(acc[qt][ot][2]) | ((unsigned)f2bf(acc[qt][ot][3]) << 16);
      *(u32x2*)&WhTb[(size_t)o * 2048 + ql] = pk;
    }
}

// ---------------------------------------------------------------------------
// Kernel B: fused masked-softmax + PV — the proven best (56.95 us total).
// Fixed per-row bound m_p (leaky monotone => valid; scale cancels exactly in
// the final division) -> no rescale, no in-loop shuffles. Double-buffered
// LDS, ONE raw barrier (lgkm drain only) per 64-q tile, reg-prefetch next
// tile across the barrier.
// ---------------------------------------------------------------------------
__global__ __launch_bounds__(512, 4) void gat_attn(
    const int* __restrict__ adj, const float* __restrict__ s,
    const __hip_bfloat16* __restrict__ WhT, float* __restrict__ out)
{
  const int N = 2048;
  const int bid = blockIdx.x;
  const int swz = (bid & 7) * 64 + (bid >> 3);   // XCD-major: batch == XCD
  const int b = swz >> 6;
  const int p0 = (swz & 63) * 32;
  const int t = threadIdx.x;
  const int wid = t >> 6, lane = t & 63;

  __shared__ __align__(16) unsigned char Bs[2][256 * 128]; // WhT tile dbuf
  __shared__ __align__(16) unsigned char Wt[2][32 * 128];  // P tile dbuf
  __shared__ __align__(16) float red_sh[8];
  __shared__ __align__(16) float l_sh[32];

  const int ep = t >> 4;              // p-row 0..31 (16 thr/row)
  const int eq4 = (t & 15) * 4;       // 4 q per thread
  const int* __restrict__ adjrow = adj + ((size_t)(b * N + p0 + ep)) * N;
  const float* __restrict__ sB = s + b * N;
  const __hip_bfloat16* __restrict__ WhTb = WhT + (size_t)b * 256 * 2048;

  const int so = t >> 3;              // Bs staging o-base 0..63
  const int q16 = t & 7;              // 16B chunk in 128B row

  // ---- prologue: prefetch tile 0 into regs ----
  i32x4 av = *(const i32x4*)&adjrow[eq4];
  f32x4 sv = *(const f32x4*)&sB[eq4];
  u32x4 breg[4];
#pragma unroll
  for (int j = 0; j < 4; ++j)
    breg[j] = *(const u32x4*)&WhTb[(size_t)(so + 64 * j) * 2048 + q16 * 8];

  // ---- block-wide smax over s[b,:] (fixed softmax bound) ----
  const f32x4 s4 = *(const f32x4*)&sB[t * 4];
  float bm = fmaxf(fmaxf(s4[0], s4[1]), fmaxf(s4[2], s4[3]));
#pragma unroll
  for (int off = 1; off < 64; off <<= 1) bm = fmaxf(bm, __shfl_xor(bm, off, 64));
  if (lane == 0) red_sh[wid] = bm;
  const float s_p = sB[p0 + ep];
  __syncthreads();
  float smax = red_sh[0];
#pragma unroll
  for (int k = 1; k < 8; ++k) smax = fmaxf(smax, red_sh[k]);
  const float xm = s_p + smax;
  const float m_p = (xm > 0.f) ? xm : (LEAKY_ALPHA * xm);

  f32x4 acc[2][2];
#pragma unroll
  for (int pt = 0; pt < 2; ++pt)
#pragma unroll
    for (int ot = 0; ot < 2; ++ot) acc[pt][ot] = (f32x4)(0.f);
  float lacc = 0.f;

#define GAT_TILE(BI, QQ)                                                      \
  do {                                                                        \
    float wv[4];                                                              \
    _Pragma("unroll")                                                         \
    for (int i = 0; i < 4; ++i) {                                             \
      const float x = s_p + sv[i];                                            \
      const float le = (x > 0.f) ? x : (LEAKY_ALPHA * x);                     \
      const float w = __expf(le - m_p);                                       \
      wv[i] = (av[i] != 0) ? w : 0.f;                                         \
      lacc += wv[i];                                                          \
    }                                                                         \
    {                                                                         \
      u32x2 pw;                                                               \
      pw[0] = (unsigned)f2bf(wv[0]) | ((unsigned)f2bf(wv[1]) << 16);          \
      pw[1] = (unsigned)f2bf(wv[2]) | ((unsigned)f2bf(wv[3]) << 16);          \
      *(u32x2*)&Wt[BI][ep * 128 + ((eq4 * 2) ^ ((ep & 7) << 4))] = pw;        \
    }                                                                         \
    _Pragma("unroll")                                                         \
    for (int j = 0; j < 4; ++j) {                                             \
      const int o = so + 64 * j;                                              \
      *(u32x4*)&Bs[BI][o * 128 + ((q16 * 16) ^ ((o & 7) << 4))] = breg[j];    \
    }                                                                         \
    if ((QQ) + 64 < N) {                                                      \
      av = *(const i32x4*)&adjrow[(QQ) + 64 + eq4];                           \
      sv = *(const f32x4*)&sB[(QQ) + 64 + eq4];                               \
      _Pragma("unroll")                                                       \
      for (int j = 0; j < 4; ++j)                                             \
        breg[j] = *(const u32x4*)&WhTb[(size_t)(so + 64 * j) * 2048 +         \
                                       (QQ) + 64 + q16 * 8];                  \
    }                                                                         \
    asm volatile("s_waitcnt lgkmcnt(0)" ::: "memory");                        \
    __builtin_amdgcn_s_barrier();                                             \
    asm volatile("" ::: "memory");                                            \
    {                                                                         \
      s16x8 afr[2][2], bfr[2][2];                                             \
      _Pragma("unroll")                                                       \
      for (int pt = 0; pt < 2; ++pt)                                          \
        _Pragma("unroll")                                                     \
        for (int kt = 0; kt < 2; ++kt) {                                      \
          const int pa = pt * 16 + (lane & 15);                               \
          const int kb = kt * 64 + ((lane >> 4) << 4);                        \
          afr[pt][kt] =                                                       \
              *(const s16x8*)&Wt[BI][pa * 128 + (kb ^ ((pa & 7) << 4))];      \
        }                                                                     \
      _Pragma("unroll")                                                       \
      for (int ot = 0; ot < 2; ++ot)                                          \
        _Pragma("unroll")                                                     \
        for (int kt = 0; kt < 2; ++kt) {                                      \
          const int ob = wid * 32 + ot * 16 + (lane & 15);                    \
          const int kb = kt * 64 + ((lane >> 4) << 4);                        \
          bfr[ot][kt] =                                                       \
              *(const s16x8*)&Bs[BI][ob * 128 + (kb ^ ((ob & 7) << 4))];      \
        }                                                                     \
      _Pragma("unroll")                                                       \
      for (int pt = 0; pt < 2; ++pt)                                          \
        _Pragma("unroll")                                                     \
        for (int ot = 0; ot < 2; ++ot)                                        \
          _Pragma("unroll")                                                   \
          for (int kt = 0; kt < 2; ++kt)                                      \
            acc[pt][ot] = __builtin_amdgcn_mfma_f32_16x16x32_bf16(            \
                afr[pt][kt], bfr[ot][kt], acc[pt][ot], 0, 0, 0);              \
    }                                                                         \
  } while (0)

  for (int q0 = 0; q0 < N; q0 += 128) {
    GAT_TILE(0, q0);
    GAT_TILE(1, q0 + 64);
  }
#undef GAT_TILE

  // ---- l reduction: 16 threads per row -> l_sh ----
  lacc += __shfl_xor(lacc, 1, 64);
  lacc += __shfl_xor(lacc, 2, 64);
  lacc += __shfl_xor(lacc, 4, 64);
  lacc += __shfl_xor(lacc, 8, 64);
  if ((t & 15) == 0) l_sh[ep] = lacc;
  __syncthreads();

  // ---- epilogue: divide by l, store fp32 ----
#pragma unroll
  for (int pt = 0; pt < 2; ++pt) {
    const f32x4 lv = *(const f32x4*)&l_sh[pt * 16 + ((lane >> 4) << 2)];
    f32x4 inv;
#pragma unroll
    for (int r = 0; r < 4; ++r) inv[r] = 1.f / lv[r];
#pragma unroll
    for (int ot = 0; ot < 2; ++ot) {
      const int o = wid * 32 + ot * 16 + (lane & 15);
#pragma unroll
      for (int r = 0; r < 4; ++r) {
        const int row = p0 + pt * 16 + ((lane >> 4) << 2) + r;
        out[((size_t)(b * N + row)) * 256 + o] = acc[pt][ot][r] * inv[r];
      }
    }
  }
}

extern "C" void kernel_launch(void* const* d_in, const int* in_sizes, int n_in,
                              void* d_out, int out_size, void* d_ws, size_t ws_size,
                              hipStream_t stream) {
  const float* h = (const float*)d_in[0];
  const int* adj = (const int*)d_in[1];
  const float* W = (const float*)d_in[2];
  float* out = (float*)d_out;

  char* ws = (char*)d_ws;
  __hip_bfloat16* WhT = (__hip_bfloat16*)ws;                              // 8 MiB
  float* s = (float*)(ws + (size_t)8 * 1024 * 1024);                      // 64 KiB
  __hip_bfloat16* WT = (__hip_bfloat16*)(ws + (size_t)8 * 1024 * 1024 + 65536);   // 128 KiB
  float* wsum = (float*)(ws + (size_t)8 * 1024 * 1024 + 65536 + 131072);  // 1 KiB

  gat_prep<<<256, 256, 0, stream>>>(W, WT, wsum);
  gat_wh2<<<512, 256, 0, stream>>>(h, WT, wsum, WhT, s);
  gat_attn<<<512, 512, 0, stream>>>(adj, s, WhT, out);
}

// Round 15
// 56.641 us; speedup vs baseline: 1.1431x; 1.0007x over previous
//
#include <hip/hip_runtime.h>
#include <hip/hip_bf16.h>
#include <stdint.h>

#define LEAKY_ALPHA 0.2f

using f32x4 = __attribute__((ext_vector_type(4))) float;
using u32x2 = __attribute__((ext_vector_type(2))) unsigned int;
using u32x4 = __attribute__((ext_vector_type(4))) unsigned int;
using i32x4 = __attribute__((ext_vector_type(4))) int;
using s16x8 = __attribute__((ext_vector_type(8))) short;

static __device__ __forceinline__ unsigned short f2bf(float x) {
  __hip_bfloat16 b = __float2bfloat16(x);
  return __builtin_bit_cast(unsigned short, b);
}

// ---------------------------------------------------------------------------
// Prep: WT[o][f] = bf16(W[f][o]);  wsum[f] = sum_o W[f][o]  (for exact fp32 s)
// ---------------------------------------------------------------------------
__global__ __launch_bounds__(256) void gat_prep(
    const float* __restrict__ W, __hip_bfloat16* __restrict__ WT,
    float* __restrict__ wsum)
{
  const int o = blockIdx.x;   // doubles as f-row index for wsum
  const int t = threadIdx.x;  // 256
  WT[o * 256 + t] = __float2bfloat16(W[t * 256 + o]);
  float u = W[o * 256 + t];
#pragma unroll
  for (int off = 1; off < 64; off <<= 1) u += __shfl_xor(u, off, 64);
  __shared__ float red[4];
  if ((t & 63) == 0) red[t >> 6] = u;
  __syncthreads();
  if (t == 0) wsum[o] = red[0] + red[1] + red[2] + red[3];
}

// ---------------------------------------------------------------------------
// Kernel A: WhT[b][o][q] = bf16( (h @ W)^T ) via MFMA; s[b][q] = h[q,:]·wsum
// (fp32 exact). q-tile 32: grid 512 -> 2-3 blocks/CU for TLP.
// Block = 32 q x 256 o, K=256 in 4 f-tiles. 512 blocks x 256 thr.
// ---------------------------------------------------------------------------
__global__ __launch_bounds__(256, 3) void gat_wh2(
    const float* __restrict__ h, const __hip_bfloat16* __restrict__ WT,
    const float* __restrict__ wsum, __hip_bfloat16* __restrict__ WhT,
    float* __restrict__ s)
{
  const int b = blockIdx.x >> 6;
  const int q0 = (blockIdx.x & 63) * 32;
  const int t = threadIdx.x;
  const int wid = t >> 6, lane = t & 63;

  __shared__ __align__(16) unsigned char Bh[32 * 512];   // h bf16 [32q][256f] swz
  __shared__ __align__(16) unsigned char Aw[256 * 128];  // WT bf16 [256o][64f] swz
  __shared__ __align__(16) float wsl[256];

  wsl[t] = wsum[t];
  __syncthreads();

  // stage h -> Bh (bf16, swizzled) with fused fp32 s computation
  {
    const int q = t >> 3;                 // 32 rows, 8 thr/row
    const int fs = (t & 7) * 32;          // 32 f per thread
    const float* hrow = h + ((size_t)(b * 2048 + q0 + q)) * 256 + fs;
    float sp = 0.f;
#pragma unroll
    for (int c = 0; c < 4; ++c) {
      const f32x4 a  = *(const f32x4*)&hrow[c * 8];
      const f32x4 bq = *(const f32x4*)&hrow[c * 8 + 4];
      const f32x4 wa = *(const f32x4*)&wsl[fs + c * 8];
      const f32x4 wb = *(const f32x4*)&wsl[fs + c * 8 + 4];
      sp += a[0]*wa[0] + a[1]*wa[1] + a[2]*wa[2] + a[3]*wa[3]
          + bq[0]*wb[0] + bq[1]*wb[1] + bq[2]*wb[2] + bq[3]*wb[3];
      u32x4 pk;
      pk[0] = (unsigned)f2bf(a[0])  | ((unsigned)f2bf(a[1])  << 16);
      pk[1] = (unsigned)f2bf(a[2])  | ((unsigned)f2bf(a[3])  << 16);
      pk[2] = (unsigned)f2bf(bq[0]) | ((unsigned)f2bf(bq[1]) << 16);
      pk[3] = (unsigned)f2bf(bq[2]) | ((unsigned)f2bf(bq[3]) << 16);
      const int boff = q * 512 + ((fs * 2 + c * 16) ^ ((q & 7) << 4));
      *(u32x4*)&Bh[boff] = pk;
    }
    sp += __shfl_xor(sp, 1, 64);
    sp += __shfl_xor(sp, 2, 64);
    sp += __shfl_xor(sp, 4, 64);
    if ((t & 7) == 0) s[b * 2048 + q0 + q] = sp;
  }

  f32x4 acc[2][4];
#pragma unroll
  for (int i = 0; i < 2; ++i)
#pragma unroll
    for (int j = 0; j < 4; ++j) acc[i][j] = (f32x4)(0.f);

  for (int it = 0; it < 4; ++it) {
    const int f0 = it * 64;
    __syncthreads();   // it=0: Bh visible; it>0: protect Aw from prev reads
#pragma unroll
    for (int j = 0; j < 8; ++j) {
      const int o = (t >> 3) + 32 * j;
      const int c = t & 7;
      const u32x4 v = *(const u32x4*)&WT[o * 256 + f0 + c * 8];
      *(u32x4*)&Aw[o * 128 + ((c * 16) ^ ((o & 7) << 4))] = v;
    }
    __syncthreads();
#pragma unroll
    for (int kt = 0; kt < 2; ++kt) {
      const int kb = kt * 64 + ((lane >> 4) << 4);   // byte off within 64-f span
      s16x8 af[2], bf[4];
#pragma unroll
      for (int qt = 0; qt < 2; ++qt) {
        const int qr = qt * 16 + (lane & 15);
        af[qt] = *(const s16x8*)&Bh[qr * 512 + ((f0 * 2 + kb) ^ ((qr & 7) << 4))];
      }
#pragma unroll
      for (int ot = 0; ot < 4; ++ot) {
        const int orow = wid * 64 + ot * 16 + (lane & 15);
        bf[ot] = *(const s16x8*)&Aw[orow * 128 + (kb ^ ((orow & 7) << 4))];
      }
#pragma unroll
      for (int qt = 0; qt < 2; ++qt)
#pragma unroll
        for (int ot = 0; ot < 4; ++ot)
          acc[qt][ot] = __builtin_amdgcn_mfma_f32_16x16x32_bf16(
              af[qt], bf[ot], acc[qt][ot], 0, 0, 0);
    }
  }

  // epilogue: WhT[b][o][q0+q]; C-row = q (r contiguous) -> 8B vector stores
  __hip_bfloat16* __restrict__ WhTb = WhT + (size_t)b * 256 * 2048;
#pragma unroll
  for (int qt = 0; qt < 2; ++qt)
#pragma unroll
    for (int ot = 0; ot < 4; ++ot) {
      const int o = wid * 64 + ot * 16 + (lane & 15);
      const int ql = q0 + qt * 16 + ((lane >> 4) << 2);
      u32x2 pk;
      pk[0] = (unsigned)f2bf(acc[qt][ot][0]) | ((unsigned)f2bf(acc[qt][ot][1]) << 16);
      pk[1] = (unsigned)f2bf(acc[qt][ot][2]) | ((unsigned)f2bf(acc[qt][ot][3]) << 16);
      *(u32x2*)&WhTb[(size_t)o * 2048 + ql] = pk;
    }
}

// ---------------------------------------------------------------------------
// Kernel B: fused masked-softmax + PV — the proven best (56.68 us total).
// Fixed per-row bound m_p (leaky monotone => valid; scale cancels exactly in
// the final division) -> no rescale, no in-loop shuffles. Double-buffered
// LDS, ONE raw barrier (lgkm drain only) per 64-q tile, reg-prefetch next
// tile across the barrier.
// ---------------------------------------------------------------------------
__global__ __launch_bounds__(512, 4) void gat_attn(
    const int* __restrict__ adj, const float* __restrict__ s,
    const __hip_bfloat16* __restrict__ WhT, float* __restrict__ out)
{
  const int N = 2048;
  const int bid = blockIdx.x;
  const int swz = (bid & 7) * 64 + (bid >> 3);   // XCD-major: batch == XCD
  const int b = swz >> 6;
  const int p0 = (swz & 63) * 32;
  const int t = threadIdx.x;
  const int wid = t >> 6, lane = t & 63;

  __shared__ __align__(16) unsigned char Bs[2][256 * 128]; // WhT tile dbuf
  __shared__ __align__(16) unsigned char Wt[2][32 * 128];  // P tile dbuf
  __shared__ __align__(16) float red_sh[8];
  __shared__ __align__(16) float l_sh[32];

  const int ep = t >> 4;              // p-row 0..31 (16 thr/row)
  const int eq4 = (t & 15) * 4;       // 4 q per thread
  const int* __restrict__ adjrow = adj + ((size_t)(b * N + p0 + ep)) * N;
  const float* __restrict__ sB = s + b * N;
  const __hip_bfloat16* __restrict__ WhTb = WhT + (size_t)b * 256 * 2048;

  const int so = t >> 3;              // Bs staging o-base 0..63
  const int q16 = t & 7;              // 16B chunk in 128B row

  // ---- prologue: prefetch tile 0 into regs ----
  i32x4 av = *(const i32x4*)&adjrow[eq4];
  f32x4 sv = *(const f32x4*)&sB[eq4];
  u32x4 breg[4];
#pragma unroll
  for (int j = 0; j < 4; ++j)
    breg[j] = *(const u32x4*)&WhTb[(size_t)(so + 64 * j) * 2048 + q16 * 8];

  // ---- block-wide smax over s[b,:] (fixed softmax bound) ----
  const f32x4 s4 = *(const f32x4*)&sB[t * 4];
  float bm = fmaxf(fmaxf(s4[0], s4[1]), fmaxf(s4[2], s4[3]));
#pragma unroll
  for (int off = 1; off < 64; off <<= 1) bm = fmaxf(bm, __shfl_xor(bm, off, 64));
  if (lane == 0) red_sh[wid] = bm;
  const float s_p = sB[p0 + ep];
  __syncthreads();
  float smax = red_sh[0];
#pragma unroll
  for (int k = 1; k < 8; ++k) smax = fmaxf(smax, red_sh[k]);
  const float xm = s_p + smax;
  const float m_p = (xm > 0.f) ? xm : (LEAKY_ALPHA * xm);

  f32x4 acc[2][2];
#pragma unroll
  for (int pt = 0; pt < 2; ++pt)
#pragma unroll
    for (int ot = 0; ot < 2; ++ot) acc[pt][ot] = (f32x4)(0.f);
  float lacc = 0.f;

#define GAT_TILE(BI, QQ)                                                      \
  do {                                                                        \
    float wv[4];                                                              \
    _Pragma("unroll")                                                         \
    for (int i = 0; i < 4; ++i) {                                             \
      const float x = s_p + sv[i];                                            \
      const float le = (x > 0.f) ? x : (LEAKY_ALPHA * x);                     \
      const float w = __expf(le - m_p);                                       \
      wv[i] = (av[i] != 0) ? w : 0.f;                                         \
      lacc += wv[i];                                                          \
    }                                                                         \
    {                                                                         \
      u32x2 pw;                                                               \
      pw[0] = (unsigned)f2bf(wv[0]) | ((unsigned)f2bf(wv[1]) << 16);          \
      pw[1] = (unsigned)f2bf(wv[2]) | ((unsigned)f2bf(wv[3]) << 16);          \
      *(u32x2*)&Wt[BI][ep * 128 + ((eq4 * 2) ^ ((ep & 7) << 4))] = pw;        \
    }                                                                         \
    _Pragma("unroll")                                                         \
    for (int j = 0; j < 4; ++j) {                                             \
      const int o = so + 64 * j;                                              \
      *(u32x4*)&Bs[BI][o * 128 + ((q16 * 16) ^ ((o & 7) << 4))] = breg[j];    \
    }                                                                         \
    if ((QQ) + 64 < N) {                                                      \
      av = *(const i32x4*)&adjrow[(QQ) + 64 + eq4];                           \
      sv = *(const f32x4*)&sB[(QQ) + 64 + eq4];                               \
      _Pragma("unroll")                                                       \
      for (int j = 0; j < 4; ++j)                                             \
        breg[j] = *(const u32x4*)&WhTb[(size_t)(so + 64 * j) * 2048 +         \
                                       (QQ) + 64 + q16 * 8];                  \
    }                                                                         \
    asm volatile("s_waitcnt lgkmcnt(0)" ::: "memory");                        \
    __builtin_amdgcn_s_barrier();                                             \
    asm volatile("" ::: "memory");                                            \
    {                                                                         \
      s16x8 afr[2][2], bfr[2][2];                                             \
      _Pragma("unroll")                                                       \
      for (int pt = 0; pt < 2; ++pt)                                          \
        _Pragma("unroll")                                                     \
        for (int kt = 0; kt < 2; ++kt) {                                      \
          const int pa = pt * 16 + (lane & 15);                               \
          const int kb = kt * 64 + ((lane >> 4) << 4);                        \
          afr[pt][kt] =                                                       \
              *(const s16x8*)&Wt[BI][pa * 128 + (kb ^ ((pa & 7) << 4))];      \
        }                                                                     \
      _Pragma("unroll")                                                       \
      for (int ot = 0; ot < 2; ++ot)                                          \
        _Pragma("unroll")                                                     \
        for (int kt = 0; kt < 2; ++kt) {                                      \
          const int ob = wid * 32 + ot * 16 + (lane & 15);                    \
          const int kb = kt * 64 + ((lane >> 4) << 4);                        \
          bfr[ot][kt] =                                                       \
              *(const s16x8*)&Bs[BI][ob * 128 + (kb ^ ((ob & 7) << 4))];      \
        }                                                                     \
      _Pragma("unroll")                                                       \
      for (int pt = 0; pt < 2; ++pt)                                          \
        _Pragma("unroll")                                                     \
        for (int ot = 0; ot < 2; ++ot)                                        \
          _Pragma("unroll")                                                   \
          for (int kt = 0; kt < 2; ++kt)                                      \
            acc[pt][ot] = __builtin_amdgcn_mfma_f32_16x16x32_bf16(            \
                afr[pt][kt], bfr[ot][kt], acc[pt][ot], 0, 0, 0);              \
    }                                                                         \
  } while (0)

  for (int q0 = 0; q0 < N; q0 += 128) {
    GAT_TILE(0, q0);
    GAT_TILE(1, q0 + 64);
  }
#undef GAT_TILE

  // ---- l reduction: 16 threads per row -> l_sh ----
  lacc += __shfl_xor(lacc, 1, 64);
  lacc += __shfl_xor(lacc, 2, 64);
  lacc += __shfl_xor(lacc, 4, 64);
  lacc += __shfl_xor(lacc, 8, 64);
  if ((t & 15) == 0) l_sh[ep] = lacc;
  __syncthreads();

  // ---- epilogue: divide by l, store fp32 ----
#pragma unroll
  for (int pt = 0; pt < 2; ++pt) {
    const f32x4 lv = *(const f32x4*)&l_sh[pt * 16 + ((lane >> 4) << 2)];
    f32x4 inv;
#pragma unroll
    for (int r = 0; r < 4; ++r) inv[r] = 1.f / lv[r];
#pragma unroll
    for (int ot = 0; ot < 2; ++ot) {
      const int o = wid * 32 + ot * 16 + (lane & 15);
#pragma unroll
      for (int r = 0; r < 4; ++r) {
        const int row = p0 + pt * 16 + ((lane >> 4) << 2) + r;
        out[((size_t)(b * N + row)) * 256 + o] = acc[pt][ot][r] * inv[r];
      }
    }
  }
}

extern "C" void kernel_launch(void* const* d_in, const int* in_sizes, int n_in,
                              void* d_out, int out_size, void* d_ws, size_t ws_size,
                              hipStream_t stream) {
  const float* h = (const float*)d_in[0];
  const int* adj = (const int*)d_in[1];
  const float* W = (const float*)d_in[2];
  float* out = (float*)d_out;

  char* ws = (char*)d_ws;
  __hip_bfloat16* WhT = (__hip_bfloat16*)ws;                              // 8 MiB
  float* s = (float*)(ws + (size_t)8 * 1024 * 1024);                      // 64 KiB
  __hip_bfloat16* WT = (__hip_bfloat16*)(ws + (size_t)8 * 1024 * 1024 + 65536);   // 128 KiB
  float* wsum = (float*)(ws + (size_t)8 * 1024 * 1024 + 65536 + 131072);  // 1 KiB

  gat_prep<<<256, 256, 0, stream>>>(W, WT, wsum);
  gat_wh2<<<512, 256, 0, stream>>>(h, WT, wsum, WhT, s);
  gat_attn<<<512, 512, 0, stream>>>(adj, s, WhT, out);
}